// Round 1
// baseline (1457.295 us; speedup 1.0000x reference)
//
#include <hip/hip_runtime.h>
#include <hip/hip_bf16.h>

#define F 64

// ---------------------------------------------------------------------------
// Stage 1: EvolveGCN-O GRU on the [64,64] weight. Thread (i,j) computes 6
// dot-64s (gx_r/z/n, gh_r/z/n) and writes W_new TRANSPOSED (wt[c][k]) so the
// xw kernel can do contiguous scalar loads of W columns.
// ---------------------------------------------------------------------------
__global__ void evolve_kernel(const float* __restrict__ W,
                              const float* __restrict__ wih,
                              const float* __restrict__ whh,
                              const float* __restrict__ bih,
                              const float* __restrict__ bhh,
                              float* __restrict__ wt) {
    int t = blockIdx.x * blockDim.x + threadIdx.x;   // 0..4095
    if (t >= F * F) return;
    int i = t >> 6;        // row of W (k-index of W_new)
    int j = t & 63;        // col (output feature)
    const float* Wi = W + i * F;
    float gxr = bih[j], gxz = bih[F + j], gxn = bih[2 * F + j];
    float ghr = bhh[j], ghz = bhh[F + j], ghn = bhh[2 * F + j];
#pragma unroll
    for (int k = 0; k < F; ++k) {
        float wv = Wi[k];
        gxr += wv * wih[(j) * F + k];
        gxz += wv * wih[(F + j) * F + k];
        gxn += wv * wih[(2 * F + j) * F + k];
        ghr += wv * whh[(j) * F + k];
        ghz += wv * whh[(F + j) * F + k];
        ghn += wv * whh[(2 * F + j) * F + k];
    }
    float r = 1.0f / (1.0f + expf(-(gxr + ghr)));
    float z = 1.0f / (1.0f + expf(-(gxz + ghz)));
    float n = tanhf(gxn + r * ghn);
    float wnew = (1.0f - z) * n + z * Wi[j];   // W_new[i][j]
    wt[j * F + i] = wnew;                      // transposed: wt[col][k]
}

// ---------------------------------------------------------------------------
// Stage 2: xw = x @ W_new. Thread-per-row: x row lives in 64 VGPRs; W reads
// are wave-uniform (loop counters only) -> compiler emits scalar s_loads of
// the 16KB WT through the constant cache. Pure-FMA bound (~5-10us).
// ---------------------------------------------------------------------------
__global__ void xw_kernel(const float* __restrict__ x,
                          const float* __restrict__ wt,
                          float* __restrict__ xw, int N) {
    int r = blockIdx.x * blockDim.x + threadIdx.x;
    if (r >= N) return;
    float xr[F];
    const float4* xp = (const float4*)(x + (size_t)r * F);
#pragma unroll
    for (int q = 0; q < F / 4; ++q) {
        float4 v = xp[q];
        xr[4 * q + 0] = v.x; xr[4 * q + 1] = v.y;
        xr[4 * q + 2] = v.z; xr[4 * q + 3] = v.w;
    }
    float4* op = (float4*)(xw + (size_t)r * F);
    for (int cb = 0; cb < F / 4; ++cb) {            // dynamic (uniform) loop
        const float* w0 = wt + (4 * cb) * F;        // 4 consecutive WT rows
        float a0 = 0.f, a1 = 0.f, a2 = 0.f, a3 = 0.f;
#pragma unroll
        for (int k = 0; k < F; ++k) {               // static -> xr stays in regs
            float xv = xr[k];
            a0 += xv * w0[k];
            a1 += xv * w0[F + k];
            a2 += xv * w0[2 * F + k];
            a3 += xv * w0[3 * F + k];
        }
        float4 o; o.x = a0; o.y = a1; o.z = a2; o.w = a3;
        op[cb] = o;
    }
}

// ---------------------------------------------------------------------------
// Stage 3: edge gather-scatter. 16 threads per edge, float4 per thread
// (256B coalesced gather per edge), 4 device-scope fp32 atomicAdds each.
// ---------------------------------------------------------------------------
__global__ void scatter_kernel(const float* __restrict__ xw,
                               const int* __restrict__ ei,
                               const float* __restrict__ ew,
                               const float* __restrict__ deg,
                               float* __restrict__ h, int E) {
    int t = blockIdx.x * blockDim.x + threadIdx.x;
    int e = t >> 4;
    int q = t & 15;
    if (e >= E) return;
    int src = ei[e];
    int dst = ei[E + e];
    float norm = ew[e] * rsqrtf(deg[src]) * rsqrtf(deg[dst]);
    const float4 v = *(const float4*)(xw + (size_t)src * F + q * 4);
    float* hp = h + (size_t)dst * F + q * 4;
    atomicAdd(hp + 0, norm * v.x);
    atomicAdd(hp + 1, norm * v.y);
    atomicAdd(hp + 2, norm * v.z);
    atomicAdd(hp + 3, norm * v.w);
}

// ---------------------------------------------------------------------------
// Stage 4: out = relu(h[:M]) @ lin_w.T + lin_b. Wave per row, shuffle reduce.
// ---------------------------------------------------------------------------
__global__ void out_kernel(const float* __restrict__ h,
                           const float* __restrict__ lw,
                           const float* __restrict__ lb,
                           float* __restrict__ out, int M) {
    int gid = blockIdx.x * blockDim.x + threadIdx.x;
    int wid = gid >> 6;
    int lane = threadIdx.x & 63;
    if (wid >= M) return;
    float v = h[(size_t)wid * F + lane];
    v = fmaxf(v, 0.0f) * lw[lane];
#pragma unroll
    for (int o = 32; o; o >>= 1) v += __shfl_xor(v, o, 64);
    if (lane == 0) out[wid] = v + lb[0];
}

extern "C" void kernel_launch(void* const* d_in, const int* in_sizes, int n_in,
                              void* d_out, int out_size, void* d_ws, size_t ws_size,
                              hipStream_t stream) {
    const float* x   = (const float*)d_in[0];
    const int*   ei  = (const int*)d_in[1];
    const float* ew  = (const float*)d_in[2];
    const float* deg = (const float*)d_in[3];
    // d_in[4] = target_num scalar; equals out_size here.
    const float* W0  = (const float*)d_in[5];
    const float* wih = (const float*)d_in[6];
    const float* whh = (const float*)d_in[7];
    const float* bih = (const float*)d_in[8];
    const float* bhh = (const float*)d_in[9];
    const float* lw  = (const float*)d_in[10];
    const float* lb  = (const float*)d_in[11];
    float* out = (float*)d_out;

    int N = in_sizes[0] / F;        // 100000
    int E = in_sizes[1] / 2;        // 1600000
    int M = out_size;               // target_num

    float* wt = (float*)d_ws;                    // 64*64 floats (transposed W_new)
    float* xw = wt + 8192;                       // N*F floats (32KB aligned offset)
    float* h  = xw + (size_t)N * F;              // N*F floats

    // evolve W (tiny)
    evolve_kernel<<<(F * F + 255) / 256, 256, 0, stream>>>(W0, wih, whh, bih, bhh, wt);

    // zero h accumulator
    hipMemsetAsync(h, 0, (size_t)N * F * sizeof(float), stream);

    // xw = x @ W_new
    xw_kernel<<<(N + 255) / 256, 256, 0, stream>>>(x, wt, xw, N);

    // edge scatter-add
    {
        long long threads = (long long)E * 16;
        int blocks = (int)((threads + 255) / 256);
        scatter_kernel<<<blocks, 256, 0, stream>>>(xw, ei, ew, deg, h, E);
    }

    // relu + linear projection
    {
        long long threads = (long long)M * 64;
        int blocks = (int)((threads + 255) / 256);
        out_kernel<<<blocks, 256, 0, stream>>>(h, lw, lb, out, M);
    }
}

// Round 2
// 366.363 us; speedup vs baseline: 3.9777x; 3.9777x over previous
//
#include <hip/hip_runtime.h>
#include <hip/hip_bf16.h>

#define F 64

// ---------------------------------------------------------------------------
// Stage 1: EvolveGCN-O GRU on the [64,64] weight. Thread (i,j) computes 6
// dot-64s and writes W_new TRANSPOSED (wt[col][k]) for the xw kernel.
// ---------------------------------------------------------------------------
__global__ void evolve_kernel(const float* __restrict__ W,
                              const float* __restrict__ wih,
                              const float* __restrict__ whh,
                              const float* __restrict__ bih,
                              const float* __restrict__ bhh,
                              float* __restrict__ wt) {
    int t = blockIdx.x * blockDim.x + threadIdx.x;   // 0..4095
    if (t >= F * F) return;
    int i = t >> 6;        // row of W
    int j = t & 63;        // col (output feature)
    const float* Wi = W + i * F;
    float gxr = bih[j], gxz = bih[F + j], gxn = bih[2 * F + j];
    float ghr = bhh[j], ghz = bhh[F + j], ghn = bhh[2 * F + j];
#pragma unroll
    for (int k = 0; k < F; ++k) {
        float wv = Wi[k];
        gxr += wv * wih[(j) * F + k];
        gxz += wv * wih[(F + j) * F + k];
        gxn += wv * wih[(2 * F + j) * F + k];
        ghr += wv * whh[(j) * F + k];
        ghz += wv * whh[(F + j) * F + k];
        ghn += wv * whh[(2 * F + j) * F + k];
    }
    float r = 1.0f / (1.0f + expf(-(gxr + ghr)));
    float z = 1.0f / (1.0f + expf(-(gxz + ghz)));
    float n = tanhf(gxn + r * ghn);
    float wnew = (1.0f - z) * n + z * Wi[j];   // W_new[i][j]
    wt[j * F + i] = wnew;                      // transposed: wt[col][k]
}

// ---------------------------------------------------------------------------
// Stage 2: xw = x @ W_new. Thread-per-row; W reads are wave-uniform ->
// scalar loads through constant cache; x row lives in VGPRs.
// ---------------------------------------------------------------------------
__global__ void xw_kernel(const float* __restrict__ x,
                          const float* __restrict__ wt,
                          float* __restrict__ xw, int N) {
    int r = blockIdx.x * blockDim.x + threadIdx.x;
    if (r >= N) return;
    float xr[F];
    const float4* xp = (const float4*)(x + (size_t)r * F);
#pragma unroll
    for (int q = 0; q < F / 4; ++q) {
        float4 v = xp[q];
        xr[4 * q + 0] = v.x; xr[4 * q + 1] = v.y;
        xr[4 * q + 2] = v.z; xr[4 * q + 3] = v.w;
    }
    float4* op = (float4*)(xw + (size_t)r * F);
    for (int cb = 0; cb < F / 4; ++cb) {            // dynamic (uniform) loop
        const float* w0 = wt + (4 * cb) * F;
        float a0 = 0.f, a1 = 0.f, a2 = 0.f, a3 = 0.f;
#pragma unroll
        for (int k = 0; k < F; ++k) {
            float xv = xr[k];
            a0 += xv * w0[k];
            a1 += xv * w0[F + k];
            a2 += xv * w0[2 * F + k];
            a3 += xv * w0[3 * F + k];
        }
        float4 o; o.x = a0; o.y = a1; o.z = a2; o.w = a3;
        op[cb] = o;
    }
}

// ---------------------------------------------------------------------------
// Stage 3a: histogram of destination nodes (int atomics, L2-resident).
// ---------------------------------------------------------------------------
__global__ void hist_kernel(const int* __restrict__ ei, int* __restrict__ counts, int E) {
    int e = blockIdx.x * blockDim.x + threadIdx.x;
    if (e >= E) return;
    atomicAdd(&counts[ei[E + e]], 1);
}

// ---------------------------------------------------------------------------
// Stage 3b: exclusive scan of counts -> offsets (3 small kernels).
// ---------------------------------------------------------------------------
__global__ void reduce_counts(const int* __restrict__ counts, int* __restrict__ bsum, int N) {
    __shared__ int s[256];
    int b = blockIdx.x, t = threadIdx.x;
    int i = b * 256 + t;
    s[t] = (i < N) ? counts[i] : 0;
    __syncthreads();
    for (int o = 128; o; o >>= 1) { if (t < o) s[t] += s[t + o]; __syncthreads(); }
    if (t == 0) bsum[b] = s[0];
}

__global__ void scan_blocksums(const int* __restrict__ bsum, int* __restrict__ bscan, int nb) {
    __shared__ int s[1024];
    int t = threadIdx.x;
    int v0 = (t < nb) ? bsum[t] : 0;
    s[t] = v0;
    __syncthreads();
    for (int o = 1; o < 1024; o <<= 1) {
        int v = (t >= o) ? s[t - o] : 0;
        __syncthreads();
        s[t] += v;
        __syncthreads();
    }
    if (t < nb) bscan[t] = s[t] - v0;   // exclusive
}

__global__ void scan_counts(const int* __restrict__ counts, const int* __restrict__ bscan,
                            int* __restrict__ offsets, int* __restrict__ cursor, int N) {
    __shared__ int s[256];
    int b = blockIdx.x, t = threadIdx.x;
    int i = b * 256 + t;
    int c = (i < N) ? counts[i] : 0;
    s[t] = c;
    __syncthreads();
    for (int o = 1; o < 256; o <<= 1) {
        int v = (t >= o) ? s[t - o] : 0;
        __syncthreads();
        s[t] += v;
        __syncthreads();
    }
    if (i < N) {
        int excl = bscan[b] + s[t] - c;
        offsets[i] = excl;
        cursor[i] = excl;
        if (i == N - 1) offsets[N] = excl + c;   // == E
    }
}

// ---------------------------------------------------------------------------
// Stage 3c: reorder edges into dst-sorted buckets, precomputing norm.
// ---------------------------------------------------------------------------
__global__ void reorder_kernel(const int* __restrict__ ei, const float* __restrict__ ew,
                               const float* __restrict__ deg, int* __restrict__ cursor,
                               int* __restrict__ s_src, float* __restrict__ s_nrm, int E) {
    int e = blockIdx.x * blockDim.x + threadIdx.x;
    if (e >= E) return;
    int src = ei[e];
    int dst = ei[E + e];
    float nm = ew[e] * rsqrtf(deg[src]) * rsqrtf(deg[dst]);
    int pos = atomicAdd(&cursor[dst], 1);
    s_src[pos] = src;
    s_nrm[pos] = nm;
}

// ---------------------------------------------------------------------------
// Stage 4: wave-per-node segment sum fused with ReLU + lin projection.
// lane = feature. Per edge: broadcast (src,norm) + coalesced 256B row gather.
// ---------------------------------------------------------------------------
__global__ void segsum_kernel(const float* __restrict__ xw,
                              const int* __restrict__ offsets,
                              const int* __restrict__ s_src,
                              const float* __restrict__ s_nrm,
                              const float* __restrict__ lw,
                              const float* __restrict__ lb,
                              float* __restrict__ out, int M) {
    int gid = blockIdx.x * blockDim.x + threadIdx.x;
    int node = gid >> 6;
    int lane = threadIdx.x & 63;
    if (node >= M) return;
    int beg = offsets[node];
    int end = offsets[node + 1];
    float acc = 0.0f;
    int e = beg;
    for (; e + 1 < end; e += 2) {                 // unroll 2 for load ILP
        int s0 = s_src[e];     float n0 = s_nrm[e];
        int s1 = s_src[e + 1]; float n1 = s_nrm[e + 1];
        float v0 = xw[(size_t)s0 * F + lane];
        float v1 = xw[(size_t)s1 * F + lane];
        acc += n0 * v0;
        acc += n1 * v1;
    }
    if (e < end) {
        int s0 = s_src[e];
        acc += s_nrm[e] * xw[(size_t)s0 * F + lane];
    }
    acc = fmaxf(acc, 0.0f) * lw[lane];
#pragma unroll
    for (int o = 32; o; o >>= 1) acc += __shfl_xor(acc, o, 64);
    if (lane == 0) out[node] = acc + lb[0];
}

extern "C" void kernel_launch(void* const* d_in, const int* in_sizes, int n_in,
                              void* d_out, int out_size, void* d_ws, size_t ws_size,
                              hipStream_t stream) {
    const float* x   = (const float*)d_in[0];
    const int*   ei  = (const int*)d_in[1];
    const float* ew  = (const float*)d_in[2];
    const float* deg = (const float*)d_in[3];
    const float* W0  = (const float*)d_in[5];
    const float* wih = (const float*)d_in[6];
    const float* whh = (const float*)d_in[7];
    const float* bih = (const float*)d_in[8];
    const float* bhh = (const float*)d_in[9];
    const float* lw  = (const float*)d_in[10];
    const float* lb  = (const float*)d_in[11];
    float* out = (float*)d_out;

    int N = in_sizes[0] / F;        // 100000
    int E = in_sizes[1] / 2;        // 1600000
    int M = out_size;               // target_num

    // workspace layout (floats/ints are 4B each)
    float* wt      = (float*)d_ws;                       // 4096 (pad to 8192)
    float* xw      = wt + 8192;                          // N*F
    int*   counts  = (int*)(xw + (size_t)N * F);         // N
    int*   offsets = counts + N;                         // N+1
    int*   cursor  = offsets + N + 2;                    // N
    int*   bsum    = cursor + N;                         // <=1024
    int*   bscan   = bsum + 1024;                        // <=1024
    int*   s_src   = bscan + 1024;                       // E
    float* s_nrm   = (float*)(s_src + E);                // E

    int nb = (N + 255) / 256;   // scan blocks (391 <= 1024)

    evolve_kernel<<<(F * F + 255) / 256, 256, 0, stream>>>(W0, wih, whh, bih, bhh, wt);

    hipMemsetAsync(counts, 0, (size_t)N * sizeof(int), stream);

    xw_kernel<<<(N + 255) / 256, 256, 0, stream>>>(x, wt, xw, N);

    hist_kernel<<<(E + 255) / 256, 256, 0, stream>>>(ei, counts, E);

    reduce_counts<<<nb, 256, 0, stream>>>(counts, bsum, N);
    scan_blocksums<<<1, 1024, 0, stream>>>(bsum, bscan, nb);
    scan_counts<<<nb, 256, 0, stream>>>(counts, bscan, offsets, cursor, N);

    reorder_kernel<<<(E + 255) / 256, 256, 0, stream>>>(ei, ew, deg, cursor, s_src, s_nrm, E);

    {
        long long threads = (long long)M * 64;
        int blocks = (int)((threads + 255) / 256);
        segsum_kernel<<<blocks, 256, 0, stream>>>(xw, offsets, s_src, s_nrm, lw, lb, out, M);
    }
}

// Round 3
// 335.487 us; speedup vs baseline: 4.3438x; 1.0920x over previous
//
#include <hip/hip_runtime.h>
#include <hip/hip_bf16.h>

#define F 64
#define NPART 8

// ---------------------------------------------------------------------------
// Stage 1: EvolveGCN-O GRU on the [64,64] weight. Thread (i,j) computes 6
// dot-64s and writes W_new TRANSPOSED (wt[col][k]) for the xw kernel.
// ---------------------------------------------------------------------------
__global__ void evolve_kernel(const float* __restrict__ W,
                              const float* __restrict__ wih,
                              const float* __restrict__ whh,
                              const float* __restrict__ bih,
                              const float* __restrict__ bhh,
                              float* __restrict__ wt) {
    int t = blockIdx.x * blockDim.x + threadIdx.x;   // 0..4095
    if (t >= F * F) return;
    int i = t >> 6;        // row of W
    int j = t & 63;        // col (output feature)
    const float* Wi = W + i * F;
    float gxr = bih[j], gxz = bih[F + j], gxn = bih[2 * F + j];
    float ghr = bhh[j], ghz = bhh[F + j], ghn = bhh[2 * F + j];
#pragma unroll
    for (int k = 0; k < F; ++k) {
        float wv = Wi[k];
        gxr += wv * wih[(j) * F + k];
        gxz += wv * wih[(F + j) * F + k];
        gxn += wv * wih[(2 * F + j) * F + k];
        ghr += wv * whh[(j) * F + k];
        ghz += wv * whh[(F + j) * F + k];
        ghn += wv * whh[(2 * F + j) * F + k];
    }
    float r = 1.0f / (1.0f + expf(-(gxr + ghr)));
    float z = 1.0f / (1.0f + expf(-(gxz + ghz)));
    float n = tanhf(gxn + r * ghn);
    float wnew = (1.0f - z) * n + z * Wi[j];   // W_new[i][j]
    wt[j * F + i] = wnew;                      // transposed: wt[col][k]
}

// ---------------------------------------------------------------------------
// Stage 2: xw = x @ W_new. Thread-per-row; W reads are wave-uniform ->
// scalar loads through constant cache; x row lives in VGPRs.
// ---------------------------------------------------------------------------
__global__ void xw_kernel(const float* __restrict__ x,
                          const float* __restrict__ wt,
                          float* __restrict__ xw, int N) {
    int r = blockIdx.x * blockDim.x + threadIdx.x;
    if (r >= N) return;
    float xr[F];
    const float4* xp = (const float4*)(x + (size_t)r * F);
#pragma unroll
    for (int q = 0; q < F / 4; ++q) {
        float4 v = xp[q];
        xr[4 * q + 0] = v.x; xr[4 * q + 1] = v.y;
        xr[4 * q + 2] = v.z; xr[4 * q + 3] = v.w;
    }
    float4* op = (float4*)(xw + (size_t)r * F);
    for (int cb = 0; cb < F / 4; ++cb) {            // dynamic (uniform) loop
        const float* w0 = wt + (4 * cb) * F;
        float a0 = 0.f, a1 = 0.f, a2 = 0.f, a3 = 0.f;
#pragma unroll
        for (int k = 0; k < F; ++k) {
            float xv = xr[k];
            a0 += xv * w0[k];
            a1 += xv * w0[F + k];
            a2 += xv * w0[2 * F + k];
            a3 += xv * w0[3 * F + k];
        }
        float4 o; o.x = a0; o.y = a1; o.z = a2; o.w = a3;
        op[cb] = o;
    }
}

// ---------------------------------------------------------------------------
// Stage 3a: histogram of destination nodes (int atomics, cache-resident).
// ---------------------------------------------------------------------------
__global__ void hist_kernel(const int* __restrict__ ei, int* __restrict__ counts, int E) {
    int e = blockIdx.x * blockDim.x + threadIdx.x;
    if (e >= E) return;
    atomicAdd(&counts[ei[E + e]], 1);
}

// ---------------------------------------------------------------------------
// Stage 3b: exclusive scan of counts -> offsets (3 small kernels).
// ---------------------------------------------------------------------------
__global__ void reduce_counts(const int* __restrict__ counts, int* __restrict__ bsum, int N) {
    __shared__ int s[256];
    int b = blockIdx.x, t = threadIdx.x;
    int i = b * 256 + t;
    s[t] = (i < N) ? counts[i] : 0;
    __syncthreads();
    for (int o = 128; o; o >>= 1) { if (t < o) s[t] += s[t + o]; __syncthreads(); }
    if (t == 0) bsum[b] = s[0];
}

__global__ void scan_blocksums(const int* __restrict__ bsum, int* __restrict__ bscan, int nb) {
    __shared__ int s[1024];
    int t = threadIdx.x;
    int v0 = (t < nb) ? bsum[t] : 0;
    s[t] = v0;
    __syncthreads();
    for (int o = 1; o < 1024; o <<= 1) {
        int v = (t >= o) ? s[t - o] : 0;
        __syncthreads();
        s[t] += v;
        __syncthreads();
    }
    if (t < nb) bscan[t] = s[t] - v0;   // exclusive
}

__global__ void scan_counts(const int* __restrict__ counts, const int* __restrict__ bscan,
                            int* __restrict__ offsets, int* __restrict__ cursor, int N) {
    __shared__ int s[256];
    int b = blockIdx.x, t = threadIdx.x;
    int i = b * 256 + t;
    int c = (i < N) ? counts[i] : 0;
    s[t] = c;
    __syncthreads();
    for (int o = 1; o < 256; o <<= 1) {
        int v = (t >= o) ? s[t - o] : 0;
        __syncthreads();
        s[t] += v;
        __syncthreads();
    }
    if (i < N) {
        int excl = bscan[b] + s[t] - c;
        offsets[i] = excl;
        cursor[i] = excl;
        if (i == N - 1) offsets[N] = excl + c;   // == E
    }
}

// ---------------------------------------------------------------------------
// Stage 3c: XCD-partitioned reorder. Block bid%8 == part handles only edges
// whose dst falls in part's contiguous node range; with round-robin block->XCD
// dispatch, each 1.6MB output window is written by a single XCD's L2 (lines
// coalesce, single writeback). Packed 8B (src, norm) payload.
// Pure locality heuristic: correct regardless of actual XCD mapping.
// ---------------------------------------------------------------------------
#define REORDER_UNROLL 8
__global__ void reorder_part_kernel(const int* __restrict__ ei, const float* __restrict__ ew,
                                    const float* __restrict__ deg, int* __restrict__ cursor,
                                    int2* __restrict__ s_pk, int E, int part_sz) {
    int part  = blockIdx.x & (NPART - 1);
    int chunk = blockIdx.x >> 3;
    int lo = part * part_sz;
    int hi = lo + part_sz;
    int base = chunk * (blockDim.x * REORDER_UNROLL);
#pragma unroll
    for (int u = 0; u < REORDER_UNROLL; ++u) {
        int e = base + u * blockDim.x + threadIdx.x;
        if (e < E) {
            int dst = ei[E + e];
            if (dst >= lo && dst < hi) {
                int src = ei[e];
                float nm = ew[e] * rsqrtf(deg[src]) * rsqrtf(deg[dst]);
                int pos = atomicAdd(&cursor[dst], 1);
                s_pk[pos] = make_int2(src, __float_as_int(nm));
            }
        }
    }
}

// ---------------------------------------------------------------------------
// Stage 4: wave-per-node segment sum fused with ReLU + lin projection.
// lane = feature. Per edge: broadcast packed (src,norm) + coalesced 256B row.
// ---------------------------------------------------------------------------
__global__ void segsum_kernel(const float* __restrict__ xw,
                              const int* __restrict__ offsets,
                              const int2* __restrict__ s_pk,
                              const float* __restrict__ lw,
                              const float* __restrict__ lb,
                              float* __restrict__ out, int M) {
    int gid = blockIdx.x * blockDim.x + threadIdx.x;
    int node = gid >> 6;
    int lane = threadIdx.x & 63;
    if (node >= M) return;
    int beg = offsets[node];
    int end = offsets[node + 1];
    float acc = 0.0f;
    int e = beg;
    for (; e + 1 < end; e += 2) {                 // unroll 2 for load ILP
        int2 p0 = s_pk[e];
        int2 p1 = s_pk[e + 1];
        float v0 = xw[(size_t)p0.x * F + lane];
        float v1 = xw[(size_t)p1.x * F + lane];
        acc += __int_as_float(p0.y) * v0;
        acc += __int_as_float(p1.y) * v1;
    }
    if (e < end) {
        int2 p0 = s_pk[e];
        acc += __int_as_float(p0.y) * xw[(size_t)p0.x * F + lane];
    }
    acc = fmaxf(acc, 0.0f) * lw[lane];
#pragma unroll
    for (int o = 32; o; o >>= 1) acc += __shfl_xor(acc, o, 64);
    if (lane == 0) out[node] = acc + lb[0];
}

extern "C" void kernel_launch(void* const* d_in, const int* in_sizes, int n_in,
                              void* d_out, int out_size, void* d_ws, size_t ws_size,
                              hipStream_t stream) {
    const float* x   = (const float*)d_in[0];
    const int*   ei  = (const int*)d_in[1];
    const float* ew  = (const float*)d_in[2];
    const float* deg = (const float*)d_in[3];
    const float* W0  = (const float*)d_in[5];
    const float* wih = (const float*)d_in[6];
    const float* whh = (const float*)d_in[7];
    const float* bih = (const float*)d_in[8];
    const float* bhh = (const float*)d_in[9];
    const float* lw  = (const float*)d_in[10];
    const float* lb  = (const float*)d_in[11];
    float* out = (float*)d_out;

    int N = in_sizes[0] / F;        // 100000
    int E = in_sizes[1] / 2;        // 1600000
    int M = out_size;               // target_num

    // workspace layout (all regions padded to multiples of 4 elements -> s_pk 8B-aligned)
    float* wt      = (float*)d_ws;                       // 8192 floats (32KB)
    float* xw      = wt + 8192;                          // N*F
    int*   counts  = (int*)(xw + (size_t)N * F);         // N
    int*   offsets = counts + ((N + 3) & ~3);            // N+1
    int*   cursor  = offsets + ((N + 4 + 3) & ~3);       // N
    int*   bsum    = cursor + ((N + 3) & ~3);            // <=1024
    int*   bscan   = bsum + 1024;                        // <=1024
    int2*  s_pk    = (int2*)(bscan + 1024);              // E packed (src, norm)

    int nb = (N + 255) / 256;   // scan blocks (391 <= 1024)
    int part_sz = (N + NPART - 1) / NPART;

    evolve_kernel<<<(F * F + 255) / 256, 256, 0, stream>>>(W0, wih, whh, bih, bhh, wt);

    hipMemsetAsync(counts, 0, (size_t)N * sizeof(int), stream);

    xw_kernel<<<(N + 255) / 256, 256, 0, stream>>>(x, wt, xw, N);

    hist_kernel<<<(E + 255) / 256, 256, 0, stream>>>(ei, counts, E);

    reduce_counts<<<nb, 256, 0, stream>>>(counts, bsum, N);
    scan_blocksums<<<1, 1024, 0, stream>>>(bsum, bscan, nb);
    scan_counts<<<nb, 256, 0, stream>>>(counts, bscan, offsets, cursor, N);

    {
        int epb = 256 * REORDER_UNROLL;                 // edges per block chunk
        int C = (E + epb - 1) / epb;
        reorder_part_kernel<<<NPART * C, 256, 0, stream>>>(ei, ew, deg, cursor, s_pk, E, part_sz);
    }

    {
        long long threads = (long long)M * 64;
        int blocks = (int)((threads + 255) / 256);
        segsum_kernel<<<blocks, 256, 0, stream>>>(xw, offsets, s_pk, lw, lb, out, M);
    }
}

// Round 4
// 313.292 us; speedup vs baseline: 4.6516x; 1.0708x over previous
//
#include <hip/hip_runtime.h>
#include <hip/hip_bf16.h>

#define F 64
#define NPART 8

__device__ __forceinline__ unsigned short f2bf(float f) {
    unsigned int u = __float_as_uint(f);
    unsigned int r = (u + 0x7FFFu + ((u >> 16) & 1u)) >> 16;   // RNE
    return (unsigned short)r;
}
__device__ __forceinline__ float bf2f(unsigned short h) {
    return __uint_as_float(((unsigned int)h) << 16);
}

// ---------------------------------------------------------------------------
// Stage 1: EvolveGCN-O GRU on the [64,64] weight. Thread (i,j) computes 6
// dot-64s and writes W_new TRANSPOSED (wt[col][k]) for the xw kernel.
// ---------------------------------------------------------------------------
__global__ void evolve_kernel(const float* __restrict__ W,
                              const float* __restrict__ wih,
                              const float* __restrict__ whh,
                              const float* __restrict__ bih,
                              const float* __restrict__ bhh,
                              float* __restrict__ wt) {
    int t = blockIdx.x * blockDim.x + threadIdx.x;   // 0..4095
    if (t >= F * F) return;
    int i = t >> 6;        // row of W
    int j = t & 63;        // col (output feature)
    const float* Wi = W + i * F;
    float gxr = bih[j], gxz = bih[F + j], gxn = bih[2 * F + j];
    float ghr = bhh[j], ghz = bhh[F + j], ghn = bhh[2 * F + j];
#pragma unroll
    for (int k = 0; k < F; ++k) {
        float wv = Wi[k];
        gxr += wv * wih[(j) * F + k];
        gxz += wv * wih[(F + j) * F + k];
        gxn += wv * wih[(2 * F + j) * F + k];
        ghr += wv * whh[(j) * F + k];
        ghz += wv * whh[(F + j) * F + k];
        ghn += wv * whh[(2 * F + j) * F + k];
    }
    float r = 1.0f / (1.0f + expf(-(gxr + ghr)));
    float z = 1.0f / (1.0f + expf(-(gxz + ghz)));
    float n = tanhf(gxn + r * ghn);
    float wnew = (1.0f - z) * n + z * Wi[j];   // W_new[i][j]
    wt[j * F + i] = wnew;                      // transposed: wt[col][k]
}

// ---------------------------------------------------------------------------
// Stage 2: xw16 = bf16(x @ W_new). Thread-per-row; W reads wave-uniform ->
// scalar loads; x row in VGPRs. bf16 output halves write + downstream gather.
// ---------------------------------------------------------------------------
__global__ void xw_kernel(const float* __restrict__ x,
                          const float* __restrict__ wt,
                          unsigned short* __restrict__ xw16, int N) {
    int r = blockIdx.x * blockDim.x + threadIdx.x;
    if (r >= N) return;
    float xr[F];
    const float4* xp = (const float4*)(x + (size_t)r * F);
#pragma unroll
    for (int q = 0; q < F / 4; ++q) {
        float4 v = xp[q];
        xr[4 * q + 0] = v.x; xr[4 * q + 1] = v.y;
        xr[4 * q + 2] = v.z; xr[4 * q + 3] = v.w;
    }
    ushort4* op = (ushort4*)(xw16 + (size_t)r * F);
    for (int cb = 0; cb < F / 4; ++cb) {            // dynamic (uniform) loop
        const float* w0 = wt + (4 * cb) * F;
        float a0 = 0.f, a1 = 0.f, a2 = 0.f, a3 = 0.f;
#pragma unroll
        for (int k = 0; k < F; ++k) {
            float xv = xr[k];
            a0 += xv * w0[k];
            a1 += xv * w0[F + k];
            a2 += xv * w0[2 * F + k];
            a3 += xv * w0[3 * F + k];
        }
        ushort4 o;
        o.x = f2bf(a0); o.y = f2bf(a1); o.z = f2bf(a2); o.w = f2bf(a3);
        op[cb] = o;
    }
}

// ---------------------------------------------------------------------------
// Stage 3a: histogram of destination nodes (int atomics, cache-resident),
// int4-vectorized dst stream.
// ---------------------------------------------------------------------------
__global__ void hist_kernel(const int* __restrict__ ei, int* __restrict__ counts, int E) {
    int t = blockIdx.x * blockDim.x + threadIdx.x;
    int e4 = t * 4;
    if (e4 + 3 < E) {
        int4 d = *(const int4*)(ei + E + e4);
        atomicAdd(&counts[d.x], 1);
        atomicAdd(&counts[d.y], 1);
        atomicAdd(&counts[d.z], 1);
        atomicAdd(&counts[d.w], 1);
    } else {
        for (int e = e4; e < E; ++e) atomicAdd(&counts[ei[E + e]], 1);
    }
}

// ---------------------------------------------------------------------------
// Stage 3b: exclusive scan of counts -> offsets (3 small kernels).
// ---------------------------------------------------------------------------
__global__ void reduce_counts(const int* __restrict__ counts, int* __restrict__ bsum, int N) {
    __shared__ int s[256];
    int b = blockIdx.x, t = threadIdx.x;
    int i = b * 256 + t;
    s[t] = (i < N) ? counts[i] : 0;
    __syncthreads();
    for (int o = 128; o; o >>= 1) { if (t < o) s[t] += s[t + o]; __syncthreads(); }
    if (t == 0) bsum[b] = s[0];
}

__global__ void scan_blocksums(const int* __restrict__ bsum, int* __restrict__ bscan, int nb) {
    __shared__ int s[1024];
    int t = threadIdx.x;
    int v0 = (t < nb) ? bsum[t] : 0;
    s[t] = v0;
    __syncthreads();
    for (int o = 1; o < 1024; o <<= 1) {
        int v = (t >= o) ? s[t - o] : 0;
        __syncthreads();
        s[t] += v;
        __syncthreads();
    }
    if (t < nb) bscan[t] = s[t] - v0;   // exclusive
}

__global__ void scan_counts(const int* __restrict__ counts, const int* __restrict__ bscan,
                            int* __restrict__ offsets, int* __restrict__ cursor, int N) {
    __shared__ int s[256];
    int b = blockIdx.x, t = threadIdx.x;
    int i = b * 256 + t;
    int c = (i < N) ? counts[i] : 0;
    s[t] = c;
    __syncthreads();
    for (int o = 1; o < 256; o <<= 1) {
        int v = (t >= o) ? s[t - o] : 0;
        __syncthreads();
        s[t] += v;
        __syncthreads();
    }
    if (i < N) {
        int excl = bscan[b] + s[t] - c;
        offsets[i] = excl;
        cursor[i] = excl;
        if (i == N - 1) offsets[N] = excl + c;   // == E
    }
}

// ---------------------------------------------------------------------------
// Stage 3c: XCD-partitioned reorder (block bid%8 handles one contiguous dst
// range -> each 1.6MB output window written by one XCD's L2). Packed 8B
// (src, norm). Locality heuristic only; correct under any XCD mapping.
// ---------------------------------------------------------------------------
#define REORDER_UNROLL 8
__global__ void reorder_part_kernel(const int* __restrict__ ei, const float* __restrict__ ew,
                                    const float* __restrict__ deg, int* __restrict__ cursor,
                                    int2* __restrict__ s_pk, int E, int part_sz) {
    int part  = blockIdx.x & (NPART - 1);
    int chunk = blockIdx.x >> 3;
    int lo = part * part_sz;
    int hi = lo + part_sz;
    int base = chunk * (blockDim.x * REORDER_UNROLL);
#pragma unroll
    for (int u = 0; u < REORDER_UNROLL; ++u) {
        int e = base + u * blockDim.x + threadIdx.x;
        if (e < E) {
            int dst = ei[E + e];
            if (dst >= lo && dst < hi) {
                int src = ei[e];
                float nm = ew[e] * rsqrtf(deg[src]) * rsqrtf(deg[dst]);
                int pos = atomicAdd(&cursor[dst], 1);
                s_pk[pos] = make_int2(src, __float_as_int(nm));
            }
        }
    }
}

// ---------------------------------------------------------------------------
// Stage 4: wave-per-node segment sum fused with ReLU + lin projection.
// lane = feature. Per edge: 8B broadcast (src,norm) + 128B bf16 row gather.
// Unroll 4 for gather MLP.
// ---------------------------------------------------------------------------
__global__ void segsum_kernel(const unsigned short* __restrict__ xw16,
                              const int* __restrict__ offsets,
                              const int2* __restrict__ s_pk,
                              const float* __restrict__ lw,
                              const float* __restrict__ lb,
                              float* __restrict__ out, int M) {
    int gid = blockIdx.x * blockDim.x + threadIdx.x;
    int node = gid >> 6;
    int lane = threadIdx.x & 63;
    if (node >= M) return;
    int beg = offsets[node];
    int end = offsets[node + 1];
    float acc = 0.0f;
    int e = beg;
    for (; e + 3 < end; e += 4) {
        int2 p0 = s_pk[e];
        int2 p1 = s_pk[e + 1];
        int2 p2 = s_pk[e + 2];
        int2 p3 = s_pk[e + 3];
        float v0 = bf2f(xw16[(size_t)p0.x * F + lane]);
        float v1 = bf2f(xw16[(size_t)p1.x * F + lane]);
        float v2 = bf2f(xw16[(size_t)p2.x * F + lane]);
        float v3 = bf2f(xw16[(size_t)p3.x * F + lane]);
        acc += __int_as_float(p0.y) * v0;
        acc += __int_as_float(p1.y) * v1;
        acc += __int_as_float(p2.y) * v2;
        acc += __int_as_float(p3.y) * v3;
    }
    for (; e < end; ++e) {
        int2 p = s_pk[e];
        acc += __int_as_float(p.y) * bf2f(xw16[(size_t)p.x * F + lane]);
    }
    acc = fmaxf(acc, 0.0f) * lw[lane];
#pragma unroll
    for (int o = 32; o; o >>= 1) acc += __shfl_xor(acc, o, 64);
    if (lane == 0) out[node] = acc + lb[0];
}

extern "C" void kernel_launch(void* const* d_in, const int* in_sizes, int n_in,
                              void* d_out, int out_size, void* d_ws, size_t ws_size,
                              hipStream_t stream) {
    const float* x   = (const float*)d_in[0];
    const int*   ei  = (const int*)d_in[1];
    const float* ew  = (const float*)d_in[2];
    const float* deg = (const float*)d_in[3];
    const float* W0  = (const float*)d_in[5];
    const float* wih = (const float*)d_in[6];
    const float* whh = (const float*)d_in[7];
    const float* bih = (const float*)d_in[8];
    const float* bhh = (const float*)d_in[9];
    const float* lw  = (const float*)d_in[10];
    const float* lb  = (const float*)d_in[11];
    float* out = (float*)d_out;

    int N = in_sizes[0] / F;        // 100000
    int E = in_sizes[1] / 2;        // 1600000
    int M = out_size;               // target_num

    // workspace layout (4B elements; s_pk kept 8B-aligned)
    float*          wt      = (float*)d_ws;                     // 8192 floats (32KB)
    unsigned short* xw16    = (unsigned short*)(wt + 8192);     // N*F bf16 (12.8MB)
    int*            counts  = (int*)(xw16 + (size_t)N * F);     // N
    int*            offsets = counts + ((N + 3) & ~3);          // N+1
    int*            cursor  = offsets + ((N + 4 + 3) & ~3);     // N
    int*            bsum    = cursor + ((N + 3) & ~3);          // <=1024
    int*            bscan   = bsum + 1024;                      // <=1024
    int2*           s_pk    = (int2*)(bscan + 1024);            // E packed (src, norm)

    int nb = (N + 255) / 256;   // scan blocks (391 <= 1024)
    int part_sz = (N + NPART - 1) / NPART;

    evolve_kernel<<<(F * F + 255) / 256, 256, 0, stream>>>(W0, wih, whh, bih, bhh, wt);

    hipMemsetAsync(counts, 0, (size_t)N * sizeof(int), stream);

    xw_kernel<<<(N + 255) / 256, 256, 0, stream>>>(x, wt, xw16, N);

    hist_kernel<<<((E + 3) / 4 + 255) / 256, 256, 0, stream>>>(ei, counts, E);

    reduce_counts<<<nb, 256, 0, stream>>>(counts, bsum, N);
    scan_blocksums<<<1, 1024, 0, stream>>>(bsum, bscan, nb);
    scan_counts<<<nb, 256, 0, stream>>>(counts, bscan, offsets, cursor, N);

    {
        int epb = 256 * REORDER_UNROLL;                 // edges per block chunk
        int C = (E + epb - 1) / epb;
        reorder_part_kernel<<<NPART * C, 256, 0, stream>>>(ei, ew, deg, cursor, s_pk, E, part_sz);
    }

    {
        long long threads = (long long)M * 64;
        int blocks = (int)((threads + 255) / 256);
        segsum_kernel<<<blocks, 256, 0, stream>>>(xw16, offsets, s_pk, lw, lb, out, M);
    }
}